// Round 10
// baseline (219.215 us; speedup 1.0000x reference)
//
#include <hip/hip_runtime.h>
#include <stdint.h>

typedef __attribute__((ext_vector_type(8))) short s16x8;
typedef __attribute__((ext_vector_type(4))) float f32x4;

#define MFMA16(a, b, c) __builtin_amdgcn_mfma_f32_16x16x32_bf16((a), (b), (c), 0, 0, 0)

// ---------- helpers ----------
__device__ __forceinline__ unsigned short f2bf(float f) {
    unsigned int u = __float_as_uint(f);
    return (unsigned short)((u + 0x7FFFu + ((u >> 16) & 1u)) >> 16);
}
__device__ __forceinline__ float bf2f(unsigned short h) {
    return __uint_as_float(((unsigned int)h) << 16);
}
__device__ __forceinline__ void cvt8(unsigned short* dst, const float* src) {
    const float4 f0 = *(const float4*)(src);
    const float4 f1 = *(const float4*)(src + 4);
    s16x8 v;
    v[0] = (short)f2bf(f0.x); v[1] = (short)f2bf(f0.y);
    v[2] = (short)f2bf(f0.z); v[3] = (short)f2bf(f0.w);
    v[4] = (short)f2bf(f1.x); v[5] = (short)f2bf(f1.y);
    v[6] = (short)f2bf(f1.z); v[7] = (short)f2bf(f1.w);
    *(s16x8*)dst = v;
}
// async global->LDS DMA, 16 B/lane; lds base wave-uniform, lane i lands at +i*16.
__device__ __forceinline__ void gl_lds16(const unsigned short* g, unsigned short* l) {
    __builtin_amdgcn_global_load_lds(
        (const __attribute__((address_space(1))) unsigned int*)g,
        (__attribute__((address_space(3))) unsigned int*)l,
        16, 0, 0);
}

// ---------- merged fp32 -> bf16 convert for x / Wqkv / Wfc (one launch) ----------
__global__ __launch_bounds__(256) void cvt_all(const float* __restrict__ x,
                                               const float* __restrict__ wq,
                                               const float* __restrict__ wf,
                                               unsigned short* __restrict__ xb,
                                               unsigned short* __restrict__ wqb,
                                               unsigned short* __restrict__ wfb) {
    const int blk = blockIdx.x;  // 0..3135
    const float* src;
    unsigned short* dst;
    int base;
    if (blk < 2048)      { src = x;  dst = xb;  base = blk; }
    else if (blk < 2624) { src = wq; dst = wqb; base = blk - 2048; }
    else                 { src = wf; dst = wfb; base = blk - 2624; }
    const int i = (base * 256 + threadIdx.x) * 8;
    cvt8(&dst[i], &src[i]);
}

// ---------- GEMM 128(M)x64(N), m97-style DMA staging ----------
// C[m][n] = sum_k A[m][k]*B[n][k], bf16 in. 256 thr / 4 waves (2x2);
// wave = 64x32 = 4x2 mfma_16x16x32 tiles; BK=64. LDS unpadded (DMA mapping).
template <bool OUT_F32>
__global__ __launch_bounds__(256) void gemm_mn(const unsigned short* __restrict__ A,
                                               const unsigned short* __restrict__ Bw,
                                               void* __restrict__ Cout, int K, int N) {
    const int bm = blockIdx.x, bn = blockIdx.y;
    const int t = threadIdx.x;
    const int lane = t & 63, w = t >> 6;
    const int quad = lane >> 4, col = lane & 15;
    const int wm = (w >> 1) * 64, wn = (w & 1) * 32;

    __shared__ alignas(16) unsigned short As[128 * 64];  // 16 KB, unpadded
    __shared__ alignas(16) unsigned short Bs[64 * 64];   //  8 KB, unpadded

    f32x4 acc[4][2];
#pragma unroll
    for (int i = 0; i < 4; ++i)
#pragma unroll
        for (int j = 0; j < 2; ++j) acc[i][j] = (f32x4){0.f, 0.f, 0.f, 0.f};

    const int lrow = lane >> 3;       // 0..7
    const int lcol = (lane & 7) * 8;  // 0..56 shorts
    const unsigned short* Ap = A + (size_t)(bm * 128 + w * 8 + lrow) * K + lcol;
    const unsigned short* Bp = Bw + (size_t)(bn * 64 + w * 8 + lrow) * K + lcol;

    for (int k0 = 0; k0 < K; k0 += 64) {
        __syncthreads();  // prior iter's ds_reads done
#pragma unroll
        for (int j = 0; j < 4; ++j)
            gl_lds16(Ap + (size_t)(j * 32) * K + k0, &As[(j * 32 + w * 8) * 64]);
#pragma unroll
        for (int j = 0; j < 2; ++j)
            gl_lds16(Bp + (size_t)(j * 32) * K + k0, &Bs[(j * 32 + w * 8) * 64]);
        __syncthreads();  // vmcnt(0) drain: DMA visible
#pragma unroll
        for (int s = 0; s < 2; ++s) {
            s16x8 af[4], bfr[2];
#pragma unroll
            for (int i = 0; i < 4; ++i)
                af[i] = *(const s16x8*)&As[(wm + i * 16 + col) * 64 + s * 32 + quad * 8];
#pragma unroll
            for (int j = 0; j < 2; ++j)
                bfr[j] = *(const s16x8*)&Bs[(wn + j * 16 + col) * 64 + s * 32 + quad * 8];
#pragma unroll
            for (int i = 0; i < 4; ++i)
#pragma unroll
                for (int j = 0; j < 2; ++j)
                    acc[i][j] = MFMA16(af[i], bfr[j], acc[i][j]);
        }
    }
    const int rowb = bm * 128 + wm + quad * 4;
    const int colb = bn * 64 + wn + col;
#pragma unroll
    for (int i = 0; i < 4; ++i)
#pragma unroll
        for (int j = 0; j < 2; ++j)
#pragma unroll
            for (int r = 0; r < 4; ++r) {
                size_t off = (size_t)(rowb + i * 16 + r) * N + colb + j * 16;
                if (OUT_F32) ((float*)Cout)[off] = acc[i][j][r];
                else ((unsigned short*)Cout)[off] = f2bf(acc[i][j][r]);
            }
}

// ---------- LayerNorm over 1152, IN-PLACE (bf16), + extract vT — vectorized ----------
__global__ __launch_bounds__(256) void ln_split(unsigned short* __restrict__ qkvn,
                                                const float* __restrict__ gamma,
                                                const float* __restrict__ beta,
                                                unsigned short* __restrict__ vT) {
    const int row = blockIdx.x;  // b*2048 + l
    const int b = row >> 11, l = row & 2047;
    unsigned short* rp = qkvn + (size_t)row * 1152;
    const int t = threadIdx.x;
    const bool act = t < 144;    // 144 * 8 = 1152

    float fv[8];
    float s = 0.f, s2 = 0.f;
    if (act) {
        s16x8 v = *(const s16x8*)&rp[t * 8];
#pragma unroll
        for (int e = 0; e < 8; ++e) {
            fv[e] = bf2f((unsigned short)v[e]);
            s += fv[e];
            s2 += fv[e] * fv[e];
        }
    } else {
#pragma unroll
        for (int e = 0; e < 8; ++e) fv[e] = 0.f;
    }
#pragma unroll
    for (int off = 32; off; off >>= 1) {
        s += __shfl_down(s, off);
        s2 += __shfl_down(s2, off);
    }
    __shared__ float red[8];
    const int lane = t & 63, w = t >> 6;
    if (lane == 0) { red[w] = s; red[w + 4] = s2; }
    __syncthreads();
    s = red[0] + red[1] + red[2] + red[3];
    s2 = red[4] + red[5] + red[6] + red[7];
    const float mu = s * (1.0f / 1152.0f);
    float var = s2 * (1.0f / 1152.0f) - mu * mu;
    var = fmaxf(var, 0.0f);
    const float rstd = rsqrtf(var + 1e-5f);

    if (act) {
        float4 g0 = *(const float4*)&gamma[t * 8];
        float4 g1 = *(const float4*)&gamma[t * 8 + 4];
        float4 e0 = *(const float4*)&beta[t * 8];
        float4 e1 = *(const float4*)&beta[t * 8 + 4];
        const float gg[8] = {g0.x, g0.y, g0.z, g0.w, g1.x, g1.y, g1.z, g1.w};
        const float bb[8] = {e0.x, e0.y, e0.z, e0.w, e1.x, e1.y, e1.z, e1.w};
        s16x8 o;
#pragma unroll
        for (int e = 0; e < 8; ++e)
            o[e] = (short)f2bf((fv[e] - mu) * rstd * gg[e] + bb[e]);
        *(s16x8*)&rp[t * 8] = o;
        if (t >= 8 && t < 16) {   // v head (cols 64..127) -> transposed copy
            const int d0 = t * 8 - 64;
#pragma unroll
            for (int e = 0; e < 8; ++e)
                vT[((size_t)(b * 64 + d0 + e)) * 2048 + l] = (unsigned short)o[e];
        }
    }
}

// ---------- Flash-style causal multi-query attention, WIDE waves ----------
// Round-8 analysis: LDS-BW bound (each wave re-reads full 8KB K + 8KB V per
// k-iter; 16 waves x 20KB = 320KB/CU-iter). Fix: 32 q-rows per wave (2 m-tiles)
// -> K/V reads amortized over 2x MFMA; total LDS traffic 1.35GB -> 0.81GB.
// Block 256 thr / 4 waves = 2 heads x (2 waves x 32 rows); K/V staged once for
// both heads. Grid (16 bhp, 32 qb) = 512 blocks; LDS 52224 -> 3 blocks/CU.
// Double-buffered K/V + register prefetch, ONE barrier/iter. Fixed-max softmax
// p = exp(s-12) (shift-invariant; |s|<~9, Q pre-scaled 1/8). Row-sums via MFMA
// vs ones. P round-trip wave-private (per-wave in-order LDS).
__global__ __launch_bounds__(256) void attn_kernel(const unsigned short* __restrict__ qkvn,
                                                   const unsigned short* __restrict__ vT,
                                                   unsigned short* __restrict__ obuf) {
    const int b = blockIdx.x >> 3, hp = blockIdx.x & 7;
    const int qb = 31 - blockIdx.y;  // longest tiles dispatched first
    const int t = threadIdx.x;
    const int lane = t & 63, w = t >> 6;
    const int quad = lane >> 4, col = lane & 15;
    const int hl = w >> 1, rh = w & 1;   // head-local (0..1), row-half (0..1)
    const int h = hp * 2 + hl;

    __shared__ alignas(16) unsigned short Ks[2][64][68];   // 17408 B
    __shared__ alignas(16) unsigned short Vts[2][64][68];  // 17408 B ([d][j])
    __shared__ alignas(16) unsigned short PQ[4][32][68];   // 17408 B: Q-stage, then per-wave P
    unsigned short(*Qs)[68] = (unsigned short(*)[68])PQ;   // view as [128][68]

    // ---- stage Q for both heads, pre-scaled 1/8 (exact in bf16) ----
#pragma unroll
    for (int hh = 0; hh < 2; ++hh)
#pragma unroll
        for (int pp = 0; pp < 2; ++pp) {
            const int idx = pp * 256 + t;
            const int r = idx >> 3, c = (idx & 7) * 8;
            s16x8 v = *(const s16x8*)(qkvn + (size_t)(b * 2048 + qb * 64 + r) * 1152 +
                                      128 + (hp * 2 + hh) * 64 + c);
#pragma unroll
            for (int e = 0; e < 8; ++e)
                v[e] = (short)f2bf(bf2f((unsigned short)v[e]) * 0.125f);
            *(s16x8*)&Qs[hh * 64 + r][c] = v;
        }
    __syncthreads();
    s16x8 qf[2][2];  // [m-tile][k-half]
#pragma unroll
    for (int mi = 0; mi < 2; ++mi)
#pragma unroll
        for (int kh = 0; kh < 2; ++kh)
            qf[mi][kh] = *(const s16x8*)&Qs[hl * 64 + rh * 32 + mi * 16 + col][kh * 32 + quad * 8];

    // ---- stage K/V tile 0 ----
#pragma unroll
    for (int pp = 0; pp < 2; ++pp) {
        const int idx = pp * 256 + t;
        const int r = idx >> 3, c = (idx & 7) * 8;
        *(uint4*)&Ks[0][r][c]  = *(const uint4*)(qkvn + (size_t)(b * 2048 + r) * 1152 + c);
        *(uint4*)&Vts[0][r][c] = *(const uint4*)(vT + (size_t)(b * 64 + r) * 2048 + c);
    }
    __syncthreads();  // KV0 visible; Q-frag reads done -> PQ reusable as P

    s16x8 ones;
#pragma unroll
    for (int e = 0; e < 8; ++e) ones[e] = (short)0x3F80;  // bf16 1.0

    f32x4 Oacc[2][4];
    f32x4 lacc[2] = {{0.f, 0.f, 0.f, 0.f}, {0.f, 0.f, 0.f, 0.f}};
#pragma unroll
    for (int mi = 0; mi < 2; ++mi)
#pragma unroll
        for (int nt = 0; nt < 4; ++nt) Oacc[mi][nt] = (f32x4){0.f, 0.f, 0.f, 0.f};

    unsigned short(*Ps)[68] = (unsigned short(*)[68])(PQ[w]);  // wave-private [32][68]
    const int qg0 = qb * 64 + rh * 32 + quad * 4;  // + mi*16 + r

    for (int kb = 0; kb <= qb; ++kb) {
        const int p = kb & 1;
        uint4 kreg[2], vreg[2];
        if (kb < qb) {  // issue next tile's global loads before compute
#pragma unroll
            for (int pp = 0; pp < 2; ++pp) {
                const int idx = pp * 256 + t;
                const int r = idx >> 3, c = (idx & 7) * 8;
                kreg[pp] = *(const uint4*)(qkvn + (size_t)(b * 2048 + (kb + 1) * 64 + r) * 1152 + c);
                vreg[pp] = *(const uint4*)(vT + (size_t)(b * 64 + r) * 2048 + (kb + 1) * 64 + c);
            }
        }
        const bool diag = (kb == qb);

        // S = (Q/8)K^T per nt (kf shared by both m-tiles) -> mask -> exp -> P
#pragma unroll
        for (int nt = 0; nt < 4; ++nt) {
            s16x8 kf0 = *(const s16x8*)&Ks[p][nt * 16 + col][quad * 8];
            s16x8 kf1 = *(const s16x8*)&Ks[p][nt * 16 + col][32 + quad * 8];
            f32x4 z[2];
#pragma unroll
            for (int mi = 0; mi < 2; ++mi) {
                z[mi] = (f32x4){0.f, 0.f, 0.f, 0.f};
                z[mi] = MFMA16(qf[mi][0], kf0, z[mi]);
                z[mi] = MFMA16(qf[mi][1], kf1, z[mi]);
            }
#pragma unroll
            for (int mi = 0; mi < 2; ++mi)
#pragma unroll
                for (int r = 0; r < 4; ++r) {
                    float sv = z[mi][r];
                    if (diag && (kb * 64 + nt * 16 + col > qg0 + mi * 16 + r)) sv = -1e30f;
                    Ps[mi * 16 + quad * 4 + r][nt * 16 + col] = f2bf(__expf(sv - 12.0f));
                }
        }

        s16x8 pf[2][2];
#pragma unroll
        for (int mi = 0; mi < 2; ++mi) {
            pf[mi][0] = *(const s16x8*)&Ps[mi * 16 + col][quad * 8];
            pf[mi][1] = *(const s16x8*)&Ps[mi * 16 + col][32 + quad * 8];
            lacc[mi] = MFMA16(pf[mi][0], ones, lacc[mi]);
            lacc[mi] = MFMA16(pf[mi][1], ones, lacc[mi]);
        }
#pragma unroll
        for (int nt = 0; nt < 4; ++nt) {
            s16x8 vf0 = *(const s16x8*)&Vts[p][nt * 16 + col][quad * 8];
            s16x8 vf1 = *(const s16x8*)&Vts[p][nt * 16 + col][32 + quad * 8];
#pragma unroll
            for (int mi = 0; mi < 2; ++mi) {
                Oacc[mi][nt] = MFMA16(pf[mi][0], vf0, Oacc[mi][nt]);
                Oacc[mi][nt] = MFMA16(pf[mi][1], vf1, Oacc[mi][nt]);
            }
        }

        if (kb < qb) {  // LDS-write prefetched tile into the other buffer
#pragma unroll
            for (int pp = 0; pp < 2; ++pp) {
                const int idx = pp * 256 + t;
                const int r = idx >> 3, c = (idx & 7) * 8;
                *(uint4*)&Ks[p ^ 1][r][c]  = kreg[pp];
                *(uint4*)&Vts[p ^ 1][r][c] = vreg[pp];
            }
        }
        __syncthreads();  // ONE barrier per iter
    }

    // epilogue: O / l  ->  obuf [b][l][h][64]  (bf16)
#pragma unroll
    for (int mi = 0; mi < 2; ++mi)
#pragma unroll
        for (int r = 0; r < 4; ++r) {
            float inv = 1.0f / lacc[mi][r];
            size_t base = (((size_t)b * 2048 + qg0 + mi * 16 + r) * 16 + h) * 64;
#pragma unroll
            for (int nt = 0; nt < 4; ++nt)
                obuf[base + nt * 16 + col] = f2bf(Oacc[mi][nt][r] * inv);
        }
}

// ---------- launch ----------
extern "C" void kernel_launch(void* const* d_in, const int* in_sizes, int n_in,
                              void* d_out, int out_size, void* d_ws, size_t ws_size,
                              hipStream_t stream) {
    (void)in_sizes; (void)n_in; (void)out_size; (void)ws_size;
    const float* x     = (const float*)d_in[0];  // (2,2048,1024) fp32
    const float* Wqkv  = (const float*)d_in[1];  // (1152,1024)  fp32
    const float* gamma = (const float*)d_in[2];  // (1152,)      fp32
    const float* beta  = (const float*)d_in[3];  // (1152,)      fp32
    const float* Wfc   = (const float*)d_in[4];  // (1024,1024)  fp32
    float* out = (float*)d_out;                  // (2,2048,1024) fp32

    // ws >= 22,806,528 B (proven in round 5)
    char* ws = (char*)d_ws;
    unsigned short* xb   = (unsigned short*)ws;               // 8,388,608
    unsigned short* Wqb  = (unsigned short*)(ws + 8388608);   // 2,359,296
    unsigned short* Wfb  = (unsigned short*)(ws + 10747904);  // 2,097,152
    unsigned short* qkvn = (unsigned short*)(ws + 12845056);  // 9,437,184
    unsigned short* vT   = (unsigned short*)(ws + 22282240);  //   524,288
    unsigned short* abuf = (unsigned short*)ws;               // alias xb (dead after gemm1)

    cvt_all<<<dim3(3136), 256, 0, stream>>>(x, Wqkv, Wfc, xb, Wqb, Wfb);
    gemm_mn<false><<<dim3(32, 18), 256, 0, stream>>>(xb, Wqb, qkvn, 1024, 1152);
    ln_split<<<dim3(4096), 256, 0, stream>>>(qkvn, gamma, beta, vT);
    attn_kernel<<<dim3(16, 32), 256, 0, stream>>>(qkvn, vT, abuf);
    gemm_mn<true><<<dim3(32, 16), 256, 0, stream>>>(abuf, Wfb, out, 1024, 1024);
}

// Round 11
// 184.151 us; speedup vs baseline: 1.1904x; 1.1904x over previous
//
#include <hip/hip_runtime.h>
#include <stdint.h>

typedef __attribute__((ext_vector_type(8))) short s16x8;
typedef __attribute__((ext_vector_type(4))) float f32x4;

#define MFMA16(a, b, c) __builtin_amdgcn_mfma_f32_16x16x32_bf16((a), (b), (c), 0, 0, 0)

// ---------- helpers ----------
__device__ __forceinline__ unsigned short f2bf(float f) {
    unsigned int u = __float_as_uint(f);
    return (unsigned short)((u + 0x7FFFu + ((u >> 16) & 1u)) >> 16);
}
__device__ __forceinline__ float bf2f(unsigned short h) {
    return __uint_as_float(((unsigned int)h) << 16);
}
__device__ __forceinline__ void cvt8(unsigned short* dst, const float* src) {
    const float4 f0 = *(const float4*)(src);
    const float4 f1 = *(const float4*)(src + 4);
    s16x8 v;
    v[0] = (short)f2bf(f0.x); v[1] = (short)f2bf(f0.y);
    v[2] = (short)f2bf(f0.z); v[3] = (short)f2bf(f0.w);
    v[4] = (short)f2bf(f1.x); v[5] = (short)f2bf(f1.y);
    v[6] = (short)f2bf(f1.z); v[7] = (short)f2bf(f1.w);
    *(s16x8*)dst = v;
}
// async global->LDS DMA, 16 B/lane; LDS base wave-uniform, lane i -> base+i*16.
// Global address is PER-LANE (gather ok). Completion via __syncthreads vmcnt drain.
__device__ __forceinline__ void gl_lds16(const unsigned short* g, unsigned short* l) {
    __builtin_amdgcn_global_load_lds(
        (const __attribute__((address_space(1))) unsigned int*)g,
        (__attribute__((address_space(3))) unsigned int*)l,
        16, 0, 0);
}

// ---------- merged fp32 -> bf16 convert for x / Wqkv / Wfc (one launch) ----------
__global__ __launch_bounds__(256) void cvt_all(const float* __restrict__ x,
                                               const float* __restrict__ wq,
                                               const float* __restrict__ wf,
                                               unsigned short* __restrict__ xb,
                                               unsigned short* __restrict__ wqb,
                                               unsigned short* __restrict__ wfb) {
    const int blk = blockIdx.x;  // 0..3135
    const float* src;
    unsigned short* dst;
    int base;
    if (blk < 2048)      { src = x;  dst = xb;  base = blk; }
    else if (blk < 2624) { src = wq; dst = wqb; base = blk - 2048; }
    else                 { src = wf; dst = wfb; base = blk - 2624; }
    const int i = (base * 256 + threadIdx.x) * 8;
    cvt8(&dst[i], &src[i]);
}

// ---------- GEMM 128(M)x64(N), m97-style DMA staging (unchanged from r9) ----------
template <bool OUT_F32>
__global__ __launch_bounds__(256) void gemm_mn(const unsigned short* __restrict__ A,
                                               const unsigned short* __restrict__ Bw,
                                               void* __restrict__ Cout, int K, int N) {
    const int bm = blockIdx.x, bn = blockIdx.y;
    const int t = threadIdx.x;
    const int lane = t & 63, w = t >> 6;
    const int quad = lane >> 4, col = lane & 15;
    const int wm = (w >> 1) * 64, wn = (w & 1) * 32;

    __shared__ alignas(16) unsigned short As[128 * 64];  // 16 KB, unpadded
    __shared__ alignas(16) unsigned short Bs[64 * 64];   //  8 KB, unpadded

    f32x4 acc[4][2];
#pragma unroll
    for (int i = 0; i < 4; ++i)
#pragma unroll
        for (int j = 0; j < 2; ++j) acc[i][j] = (f32x4){0.f, 0.f, 0.f, 0.f};

    const int lrow = lane >> 3;       // 0..7
    const int lcol = (lane & 7) * 8;  // 0..56 shorts
    const unsigned short* Ap = A + (size_t)(bm * 128 + w * 8 + lrow) * K + lcol;
    const unsigned short* Bp = Bw + (size_t)(bn * 64 + w * 8 + lrow) * K + lcol;

    for (int k0 = 0; k0 < K; k0 += 64) {
        __syncthreads();  // prior iter's ds_reads done
#pragma unroll
        for (int j = 0; j < 4; ++j)
            gl_lds16(Ap + (size_t)(j * 32) * K + k0, &As[(j * 32 + w * 8) * 64]);
#pragma unroll
        for (int j = 0; j < 2; ++j)
            gl_lds16(Bp + (size_t)(j * 32) * K + k0, &Bs[(j * 32 + w * 8) * 64]);
        __syncthreads();  // vmcnt(0) drain: DMA visible
#pragma unroll
        for (int s = 0; s < 2; ++s) {
            s16x8 af[4], bfr[2];
#pragma unroll
            for (int i = 0; i < 4; ++i)
                af[i] = *(const s16x8*)&As[(wm + i * 16 + col) * 64 + s * 32 + quad * 8];
#pragma unroll
            for (int j = 0; j < 2; ++j)
                bfr[j] = *(const s16x8*)&Bs[(wn + j * 16 + col) * 64 + s * 32 + quad * 8];
#pragma unroll
            for (int i = 0; i < 4; ++i)
#pragma unroll
                for (int j = 0; j < 2; ++j)
                    acc[i][j] = MFMA16(af[i], bfr[j], acc[i][j]);
        }
    }
    const int rowb = bm * 128 + wm + quad * 4;
    const int colb = bn * 64 + wn + col;
#pragma unroll
    for (int i = 0; i < 4; ++i)
#pragma unroll
        for (int j = 0; j < 2; ++j)
#pragma unroll
            for (int r = 0; r < 4; ++r) {
                size_t off = (size_t)(rowb + i * 16 + r) * N + colb + j * 16;
                if (OUT_F32) ((float*)Cout)[off] = acc[i][j][r];
                else ((unsigned short*)Cout)[off] = f2bf(acc[i][j][r]);
            }
}

// ---------- LayerNorm over 1152, IN-PLACE (bf16), + extract vT (unchanged) ----------
__global__ __launch_bounds__(256) void ln_split(unsigned short* __restrict__ qkvn,
                                                const float* __restrict__ gamma,
                                                const float* __restrict__ beta,
                                                unsigned short* __restrict__ vT) {
    const int row = blockIdx.x;  // b*2048 + l
    const int b = row >> 11, l = row & 2047;
    unsigned short* rp = qkvn + (size_t)row * 1152;
    const int t = threadIdx.x;
    const bool act = t < 144;    // 144 * 8 = 1152

    float fv[8];
    float s = 0.f, s2 = 0.f;
    if (act) {
        s16x8 v = *(const s16x8*)&rp[t * 8];
#pragma unroll
        for (int e = 0; e < 8; ++e) {
            fv[e] = bf2f((unsigned short)v[e]);
            s += fv[e];
            s2 += fv[e] * fv[e];
        }
    } else {
#pragma unroll
        for (int e = 0; e < 8; ++e) fv[e] = 0.f;
    }
#pragma unroll
    for (int off = 32; off; off >>= 1) {
        s += __shfl_down(s, off);
        s2 += __shfl_down(s2, off);
    }
    __shared__ float red[8];
    const int lane = t & 63, w = t >> 6;
    if (lane == 0) { red[w] = s; red[w + 4] = s2; }
    __syncthreads();
    s = red[0] + red[1] + red[2] + red[3];
    s2 = red[4] + red[5] + red[6] + red[7];
    const float mu = s * (1.0f / 1152.0f);
    float var = s2 * (1.0f / 1152.0f) - mu * mu;
    var = fmaxf(var, 0.0f);
    const float rstd = rsqrtf(var + 1e-5f);

    if (act) {
        float4 g0 = *(const float4*)&gamma[t * 8];
        float4 g1 = *(const float4*)&gamma[t * 8 + 4];
        float4 e0 = *(const float4*)&beta[t * 8];
        float4 e1 = *(const float4*)&beta[t * 8 + 4];
        const float gg[8] = {g0.x, g0.y, g0.z, g0.w, g1.x, g1.y, g1.z, g1.w};
        const float bb[8] = {e0.x, e0.y, e0.z, e0.w, e1.x, e1.y, e1.z, e1.w};
        s16x8 o;
#pragma unroll
        for (int e = 0; e < 8; ++e)
            o[e] = (short)f2bf((fv[e] - mu) * rstd * gg[e] + bb[e]);
        *(s16x8*)&rp[t * 8] = o;
        if (t >= 8 && t < 16) {   // v head (cols 64..127) -> transposed copy
            const int d0 = t * 8 - 64;
#pragma unroll
            for (int e = 0; e < 8; ++e)
                vT[((size_t)(b * 64 + d0 + e)) * 2048 + l] = (unsigned short)o[e];
        }
    }
}

// ---------- Flash-style causal multi-query attention, r8 structure + DMA/swizzle ----------
// 512 thr / 8 waves / 2 heads; wave = 16 q-rows (fits the ~64-VGPR toolchain cap:
// r9/r10 wide-wave designs spilled at alloc 68). K/V staged by global_load_lds
// into XOR-swizzled UNPADDED [64][64] tiles (chunk ^= row&7 -> fragment reads hit
// all 32 banks, 2 lanes each = free). Zero staging registers; prefetch overlaps
// compute; ONE barrier/iter. Fixed-max softmax p = exp(s-12); row-sum in f32 VALU
// (lacc += p) + one end-of-kernel shfl reduction (replaces ones-MFMA, frees 8 regs).
// qb pairing (y, y+16 -> 33 iters) balances per-CU work under linear dispatch.
__global__ __launch_bounds__(512) void attn_kernel(const unsigned short* __restrict__ qkvn,
                                                   const unsigned short* __restrict__ vT,
                                                   unsigned short* __restrict__ obuf) {
    const int b = blockIdx.x >> 3, hp = blockIdx.x & 7;
    const int yy = blockIdx.y;
    const int qb = (yy < 16) ? yy : 47 - yy;   // pair (y, y+16) sums to 33 iters
    const int t = threadIdx.x;
    const int lane = t & 63, w = t >> 6;
    const int quad = lane >> 4, col = lane & 15;
    const int hl = w >> 2, wq = w & 3;   // head-local, wave-in-head
    const int h = hp * 2 + hl;

    __shared__ alignas(16) unsigned short Ks[2][4096];   // 16 KB swizzled, unpadded
    __shared__ alignas(16) unsigned short Vts[2][4096];  // 16 KB ([d][j] swizzled)
    __shared__ alignas(16) unsigned short PQ[8][16][68]; // 17408 B: Q-stage, then per-wave P
    unsigned short(*Qs)[68] = (unsigned short(*)[68])PQ; // view as [128][68]

    // ---- stage Q for both heads, pre-scaled 1/8 (exact in bf16) ----
    {
        const int r = t >> 3, c = (t & 7) * 8;  // r 0..63
#pragma unroll
        for (int hh = 0; hh < 2; ++hh) {
            s16x8 v = *(const s16x8*)(qkvn + (size_t)(b * 2048 + qb * 64 + r) * 1152 +
                                      128 + (hp * 2 + hh) * 64 + c);
#pragma unroll
            for (int e = 0; e < 8; ++e)
                v[e] = (short)f2bf(bf2f((unsigned short)v[e]) * 0.125f);
            *(s16x8*)&Qs[hh * 64 + r][c] = v;
        }
    }
    __syncthreads();
    const s16x8 qf0 = *(const s16x8*)&Qs[hl * 64 + wq * 16 + col][quad * 8];
    const s16x8 qf1 = *(const s16x8*)&Qs[hl * 64 + wq * 16 + col][32 + quad * 8];

    // ---- DMA lane mapping (XOR swizzle): wave w fills rows w*8..w*8+7 ----
    const int drow = w * 8 + (lane >> 3);
    const int dchunk = (lane & 7) ^ ((lane >> 3) & 7);
    const unsigned short* kdma = qkvn + (size_t)(b * 2048 + drow) * 1152 + dchunk * 8;
    const unsigned short* vdma = vT + (size_t)(b * 64 + drow) * 2048 + dchunk * 8;
    gl_lds16(kdma, &Ks[0][w * 512]);
    gl_lds16(vdma, &Vts[0][w * 512]);

    // fragment byte offsets into swizzled tiles (invariant across k-loop)
    const int fo0 = col * 128 + ((quad ^ (col & 7)) * 16);        // kh=0
    const int fo1 = col * 128 + (((4 + quad) ^ (col & 7)) * 16);  // kh=1

    f32x4 Oacc[4];
    f32x4 lacc = {0.f, 0.f, 0.f, 0.f};
#pragma unroll
    for (int nt = 0; nt < 4; ++nt) Oacc[nt] = (f32x4){0.f, 0.f, 0.f, 0.f};

    unsigned short(*Ps)[68] = PQ[w];             // wave-private P [16][68]
    const int qg = qb * 64 + wq * 16 + quad * 4; // + r

    __syncthreads();  // tile0 DMA drained; qf reads fenced -> PQ reusable as P

    for (int kb = 0; kb <= qb; ++kb) {
        const int p = kb & 1;
        if (kb < qb) {  // zero-register prefetch of next tile into other buffer
            gl_lds16(kdma + (size_t)(kb + 1) * (64 * 1152), &Ks[p ^ 1][w * 512]);
            gl_lds16(vdma + (kb + 1) * 64, &Vts[p ^ 1][w * 512]);
        }
        const bool diag = (kb == qb);
        const char* kb8 = (const char*)Ks[p];
        const char* vb8 = (const char*)Vts[p];

        // S = (Q/8)K^T per nt -> mask -> exp -> P write + f32 row-sum accumulate
#pragma unroll
        for (int nt = 0; nt < 4; ++nt) {
            s16x8 kf0 = *(const s16x8*)(kb8 + nt * 2048 + fo0);
            s16x8 kf1 = *(const s16x8*)(kb8 + nt * 2048 + fo1);
            f32x4 z = (f32x4){0.f, 0.f, 0.f, 0.f};
            z = MFMA16(qf0, kf0, z);
            z = MFMA16(qf1, kf1, z);
#pragma unroll
            for (int r = 0; r < 4; ++r) {
                float sv = z[r];
                if (diag && (kb * 64 + nt * 16 + col > qg + r)) sv = -1e30f;
                float pv = __expf(sv - 12.0f);
                lacc[r] += pv;
                Ps[quad * 4 + r][nt * 16 + col] = f2bf(pv);
            }
        }

        const s16x8 pf0 = *(const s16x8*)&Ps[col][quad * 8];       // wave-private, in-order
        const s16x8 pf1 = *(const s16x8*)&Ps[col][32 + quad * 8];
#pragma unroll
        for (int nt = 0; nt < 4; ++nt) {
            s16x8 vf0 = *(const s16x8*)(vb8 + nt * 2048 + fo0);
            s16x8 vf1 = *(const s16x8*)(vb8 + nt * 2048 + fo1);
            Oacc[nt] = MFMA16(pf0, vf0, Oacc[nt]);
            Oacc[nt] = MFMA16(pf1, vf1, Oacc[nt]);
        }
        __syncthreads();  // ONE barrier/iter: drains DMA, fences buffer swap
    }

    // row-sum reduction over the 16 col-lanes of this quad (lane ids contiguous)
#pragma unroll
    for (int r = 0; r < 4; ++r)
#pragma unroll
        for (int off = 1; off < 16; off <<= 1)
            lacc[r] += __shfl_xor(lacc[r], off);

    // epilogue: O / l  ->  obuf [b][l][h][64]  (bf16)
#pragma unroll
    for (int r = 0; r < 4; ++r) {
        float inv = 1.0f / lacc[r];
        size_t base = (((size_t)b * 2048 + qg + r) * 16 + h) * 64;
#pragma unroll
        for (int nt = 0; nt < 4; ++nt)
            obuf[base + nt * 16 + col] = f2bf(Oacc[nt][r] * inv);
    }
}

// ---------- launch ----------
extern "C" void kernel_launch(void* const* d_in, const int* in_sizes, int n_in,
                              void* d_out, int out_size, void* d_ws, size_t ws_size,
                              hipStream_t stream) {
    (void)in_sizes; (void)n_in; (void)out_size; (void)ws_size;
    const float* x     = (const float*)d_in[0];  // (2,2048,1024) fp32
    const float* Wqkv  = (const float*)d_in[1];  // (1152,1024)  fp32
    const float* gamma = (const float*)d_in[2];  // (1152,)      fp32
    const float* beta  = (const float*)d_in[3];  // (1152,)      fp32
    const float* Wfc   = (const float*)d_in[4];  // (1024,1024)  fp32
    float* out = (float*)d_out;                  // (2,2048,1024) fp32

    // ws >= 22,806,528 B (proven in round 5)
    char* ws = (char*)d_ws;
    unsigned short* xb   = (unsigned short*)ws;               // 8,388,608
    unsigned short* Wqb  = (unsigned short*)(ws + 8388608);   // 2,359,296
    unsigned short* Wfb  = (unsigned short*)(ws + 10747904);  // 2,097,152
    unsigned short* qkvn = (unsigned short*)(ws + 12845056);  // 9,437,184
    unsigned short* vT   = (unsigned short*)(ws + 22282240);  //   524,288
    unsigned short* abuf = (unsigned short*)ws;               // alias xb (dead after gemm1)

    cvt_all<<<dim3(3136), 256, 0, stream>>>(x, Wqkv, Wfc, xb, Wqb, Wfb);
    gemm_mn<false><<<dim3(32, 18), 256, 0, stream>>>(xb, Wqb, qkvn, 1024, 1152);
    ln_split<<<dim3(4096), 256, 0, stream>>>(qkvn, gamma, beta, vT);
    attn_kernel<<<dim3(16, 32), 512, 0, stream>>>(qkvn, vT, abuf);
    gemm_mn<true><<<dim3(32, 16), 256, 0, stream>>>(abuf, Wfb, out, 1024, 1024);
}

// Round 12
// 172.716 us; speedup vs baseline: 1.2692x; 1.0662x over previous
//
#include <hip/hip_runtime.h>
#include <stdint.h>

typedef __attribute__((ext_vector_type(8))) short s16x8;
typedef __attribute__((ext_vector_type(4))) float f32x4;

#define MFMA16(a, b, c) __builtin_amdgcn_mfma_f32_16x16x32_bf16((a), (b), (c), 0, 0, 0)

// ---------- helpers ----------
__device__ __forceinline__ unsigned short f2bf(float f) {
    unsigned int u = __float_as_uint(f);
    return (unsigned short)((u + 0x7FFFu + ((u >> 16) & 1u)) >> 16);
}
__device__ __forceinline__ float bf2f(unsigned short h) {
    return __uint_as_float(((unsigned int)h) << 16);
}
__device__ __forceinline__ void cvt8(unsigned short* dst, const float* src) {
    const float4 f0 = *(const float4*)(src);
    const float4 f1 = *(const float4*)(src + 4);
    s16x8 v;
    v[0] = (short)f2bf(f0.x); v[1] = (short)f2bf(f0.y);
    v[2] = (short)f2bf(f0.z); v[3] = (short)f2bf(f0.w);
    v[4] = (short)f2bf(f1.x); v[5] = (short)f2bf(f1.y);
    v[6] = (short)f2bf(f1.z); v[7] = (short)f2bf(f1.w);
    *(s16x8*)dst = v;
}
// async global->LDS DMA, 16 B/lane; LDS base wave-uniform, lane i -> base+i*16.
__device__ __forceinline__ void gl_lds16(const unsigned short* g, unsigned short* l) {
    __builtin_amdgcn_global_load_lds(
        (const __attribute__((address_space(1))) unsigned int*)g,
        (__attribute__((address_space(3))) unsigned int*)l,
        16, 0, 0);
}

// ---------- merged fp32 -> bf16 convert for x / Wqkv / Wfc (one launch) ----------
__global__ __launch_bounds__(256) void cvt_all(const float* __restrict__ x,
                                               const float* __restrict__ wq,
                                               const float* __restrict__ wf,
                                               unsigned short* __restrict__ xb,
                                               unsigned short* __restrict__ wqb,
                                               unsigned short* __restrict__ wfb) {
    const int blk = blockIdx.x;  // 0..3135
    const float* src;
    unsigned short* dst;
    int base;
    if (blk < 2048)      { src = x;  dst = xb;  base = blk; }
    else if (blk < 2624) { src = wq; dst = wqb; base = blk - 2048; }
    else                 { src = wf; dst = wfb; base = blk - 2624; }
    const int i = (base * 256 + threadIdx.x) * 8;
    cvt8(&dst[i], &src[i]);
}

// ---------- GEMM 128(M)x64(N), m97-style DMA staging (unchanged from r9) ----------
template <bool OUT_F32>
__global__ __launch_bounds__(256) void gemm_mn(const unsigned short* __restrict__ A,
                                               const unsigned short* __restrict__ Bw,
                                               void* __restrict__ Cout, int K, int N) {
    const int bm = blockIdx.x, bn = blockIdx.y;
    const int t = threadIdx.x;
    const int lane = t & 63, w = t >> 6;
    const int quad = lane >> 4, col = lane & 15;
    const int wm = (w >> 1) * 64, wn = (w & 1) * 32;

    __shared__ alignas(16) unsigned short As[128 * 64];  // 16 KB, unpadded
    __shared__ alignas(16) unsigned short Bs[64 * 64];   //  8 KB, unpadded

    f32x4 acc[4][2];
#pragma unroll
    for (int i = 0; i < 4; ++i)
#pragma unroll
        for (int j = 0; j < 2; ++j) acc[i][j] = (f32x4){0.f, 0.f, 0.f, 0.f};

    const int lrow = lane >> 3;       // 0..7
    const int lcol = (lane & 7) * 8;  // 0..56 shorts
    const unsigned short* Ap = A + (size_t)(bm * 128 + w * 8 + lrow) * K + lcol;
    const unsigned short* Bp = Bw + (size_t)(bn * 64 + w * 8 + lrow) * K + lcol;

    for (int k0 = 0; k0 < K; k0 += 64) {
        __syncthreads();  // prior iter's ds_reads done
#pragma unroll
        for (int j = 0; j < 4; ++j)
            gl_lds16(Ap + (size_t)(j * 32) * K + k0, &As[(j * 32 + w * 8) * 64]);
#pragma unroll
        for (int j = 0; j < 2; ++j)
            gl_lds16(Bp + (size_t)(j * 32) * K + k0, &Bs[(j * 32 + w * 8) * 64]);
        __syncthreads();  // vmcnt(0) drain: DMA visible
#pragma unroll
        for (int s = 0; s < 2; ++s) {
            s16x8 af[4], bfr[2];
#pragma unroll
            for (int i = 0; i < 4; ++i)
                af[i] = *(const s16x8*)&As[(wm + i * 16 + col) * 64 + s * 32 + quad * 8];
#pragma unroll
            for (int j = 0; j < 2; ++j)
                bfr[j] = *(const s16x8*)&Bs[(wn + j * 16 + col) * 64 + s * 32 + quad * 8];
#pragma unroll
            for (int i = 0; i < 4; ++i)
#pragma unroll
                for (int j = 0; j < 2; ++j)
                    acc[i][j] = MFMA16(af[i], bfr[j], acc[i][j]);
        }
    }
    const int rowb = bm * 128 + wm + quad * 4;
    const int colb = bn * 64 + wn + col;
#pragma unroll
    for (int i = 0; i < 4; ++i)
#pragma unroll
        for (int j = 0; j < 2; ++j)
#pragma unroll
            for (int r = 0; r < 4; ++r) {
                size_t off = (size_t)(rowb + i * 16 + r) * N + colb + j * 16;
                if (OUT_F32) ((float*)Cout)[off] = acc[i][j][r];
                else ((unsigned short*)Cout)[off] = f2bf(acc[i][j][r]);
            }
}

// ---------- LayerNorm over 1152, IN-PLACE (bf16), + extract vT (unchanged) ----------
__global__ __launch_bounds__(256) void ln_split(unsigned short* __restrict__ qkvn,
                                                const float* __restrict__ gamma,
                                                const float* __restrict__ beta,
                                                unsigned short* __restrict__ vT) {
    const int row = blockIdx.x;  // b*2048 + l
    const int b = row >> 11, l = row & 2047;
    unsigned short* rp = qkvn + (size_t)row * 1152;
    const int t = threadIdx.x;
    const bool act = t < 144;    // 144 * 8 = 1152

    float fv[8];
    float s = 0.f, s2 = 0.f;
    if (act) {
        s16x8 v = *(const s16x8*)&rp[t * 8];
#pragma unroll
        for (int e = 0; e < 8; ++e) {
            fv[e] = bf2f((unsigned short)v[e]);
            s += fv[e];
            s2 += fv[e] * fv[e];
        }
    } else {
#pragma unroll
        for (int e = 0; e < 8; ++e) fv[e] = 0.f;
    }
#pragma unroll
    for (int off = 32; off; off >>= 1) {
        s += __shfl_down(s, off);
        s2 += __shfl_down(s2, off);
    }
    __shared__ float red[8];
    const int lane = t & 63, w = t >> 6;
    if (lane == 0) { red[w] = s; red[w + 4] = s2; }
    __syncthreads();
    s = red[0] + red[1] + red[2] + red[3];
    s2 = red[4] + red[5] + red[6] + red[7];
    const float mu = s * (1.0f / 1152.0f);
    float var = s2 * (1.0f / 1152.0f) - mu * mu;
    var = fmaxf(var, 0.0f);
    const float rstd = rsqrtf(var + 1e-5f);

    if (act) {
        float4 g0 = *(const float4*)&gamma[t * 8];
        float4 g1 = *(const float4*)&gamma[t * 8 + 4];
        float4 e0 = *(const float4*)&beta[t * 8];
        float4 e1 = *(const float4*)&beta[t * 8 + 4];
        const float gg[8] = {g0.x, g0.y, g0.z, g0.w, g1.x, g1.y, g1.z, g1.w};
        const float bb[8] = {e0.x, e0.y, e0.z, e0.w, e1.x, e1.y, e1.z, e1.w};
        s16x8 o;
#pragma unroll
        for (int e = 0; e < 8; ++e)
            o[e] = (short)f2bf((fv[e] - mu) * rstd * gg[e] + bb[e]);
        *(s16x8*)&rp[t * 8] = o;
        if (t >= 8 && t < 16) {   // v head (cols 64..127) -> transposed copy
            const int d0 = t * 8 - 64;
#pragma unroll
            for (int e = 0; e < 8; ++e)
                vT[((size_t)(b * 64 + d0 + e)) * 2048 + l] = (unsigned short)o[e];
        }
    }
}

// ---------- Flash-style causal multi-query attention (EXACT r8 version, 50us) ----------
// Block: 512 thr / 8 waves, 2 heads x 64 q-rows; K/V staged once per tile for
// both heads (multi-query reuse). Double-buffered K/V + REGISTER prefetch
// (NOT DMA: r11's DMA staging regressed attn 50->60us -- DMA LDS-write
// bandwidth steal is invisible to SQ_LDS_BANK_CONFLICT and collides with the
// K/V-read-heavy loop; register staging schedules with the waves). ONE
// __syncthreads per k-iter. Fixed-max softmax p = exp(s - 12). Row-sum via
// MFMA vs ones. P round-trip wave-private (in-order LDS, no barrier).
__global__ __launch_bounds__(512) void attn_kernel(const unsigned short* __restrict__ qkvn,
                                                   const unsigned short* __restrict__ vT,
                                                   unsigned short* __restrict__ obuf) {
    const int b = blockIdx.x >> 3, hp = blockIdx.x & 7;
    const int qb = 31 - blockIdx.y;  // longest tiles dispatched first
    const int t = threadIdx.x;
    const int lane = t & 63, w = t >> 6;
    const int quad = lane >> 4, col = lane & 15;
    const int hl = w >> 2, wq = w & 3;   // head-local, wave-in-head

    __shared__ alignas(16) unsigned short Ks[2][64][72];
    __shared__ alignas(16) unsigned short Vts[2][64][72];   // [d][j]
    __shared__ alignas(16) unsigned short PQ[8][16][72];    // Q-stage, then per-wave P

    unsigned short(*Qs)[72] = (unsigned short(*)[72])PQ;    // view as [128][72]

    const int rs = t >> 3;        // 0..63
    const int cs = (t & 7) * 8;   // 0..56

    // stage Q for both heads, pre-scaled by 1/8 (exact in bf16)
#pragma unroll
    for (int hh = 0; hh < 2; ++hh) {
        const unsigned short* qsrc =
            qkvn + (size_t)(b * 2048 + qb * 64 + rs) * 1152 + 128 + (hp * 2 + hh) * 64 + cs;
        s16x8 v = *(const s16x8*)qsrc;
#pragma unroll
        for (int e = 0; e < 8; ++e)
            v[e] = (short)f2bf(bf2f((unsigned short)v[e]) * 0.125f);
        *(s16x8*)&Qs[hh * 64 + rs][cs] = v;
    }
    __syncthreads();
    const s16x8 qf0 = *(const s16x8*)&Qs[hl * 64 + wq * 16 + col][quad * 8];
    const s16x8 qf1 = *(const s16x8*)&Qs[hl * 64 + wq * 16 + col][32 + quad * 8];

    // stage K/V tile 0
    const unsigned short* kbase = qkvn + (size_t)(b * 2048 + rs) * 1152 + cs;  // + kb*64*1152
    const unsigned short* vbase = vT + (size_t)(b * 64 + rs) * 2048 + cs;      // + kb*64
    *(uint4*)&Ks[0][rs][cs]  = *(const uint4*)(kbase);
    *(uint4*)&Vts[0][rs][cs] = *(const uint4*)(vbase);
    __syncthreads();  // KV0 visible; all Q-frag reads done -> PQ reusable as P

    s16x8 ones;
#pragma unroll
    for (int e = 0; e < 8; ++e) ones[e] = (short)0x3F80;  // bf16 1.0

    f32x4 Oacc[4];
    f32x4 lacc = {0.f, 0.f, 0.f, 0.f};
#pragma unroll
    for (int nt = 0; nt < 4; ++nt) Oacc[nt] = (f32x4){0.f, 0.f, 0.f, 0.f};

    const int qg = qb * 64 + wq * 16 + quad * 4;  // + r

    for (int kb = 0; kb <= qb; ++kb) {
        const int p = kb & 1;
        uint4 kreg, vreg;
        if (kb < qb) {  // issue next tile's global loads before compute
            kreg = *(const uint4*)(kbase + (size_t)(kb + 1) * 64 * 1152);
            vreg = *(const uint4*)(vbase + (kb + 1) * 64);
        }

        // S = (Q/8) K^T  (16 x 64 per wave)
        f32x4 S[4];
#pragma unroll
        for (int nt = 0; nt < 4; ++nt) {
            s16x8 kf0 = *(const s16x8*)&Ks[p][nt * 16 + col][quad * 8];
            s16x8 kf1 = *(const s16x8*)&Ks[p][nt * 16 + col][32 + quad * 8];
            f32x4 z = (f32x4){0.f, 0.f, 0.f, 0.f};
            z = MFMA16(qf0, kf0, z);
            z = MFMA16(qf1, kf1, z);
            S[nt] = z;
        }
        if (kb == qb) {  // causal mask on diagonal tile only
#pragma unroll
            for (int nt = 0; nt < 4; ++nt)
#pragma unroll
                for (int r = 0; r < 4; ++r)
                    if (kb * 64 + nt * 16 + col > qg + r) S[nt][r] = -1e30f;
        }

        // P = exp(S - 12): C-layout -> LDS -> A-layout (wave-private, no barrier)
#pragma unroll
        for (int nt = 0; nt < 4; ++nt)
#pragma unroll
            for (int r = 0; r < 4; ++r)
                PQ[w][quad * 4 + r][nt * 16 + col] = f2bf(__expf(S[nt][r] - 12.0f));

        const s16x8 pf0 = *(const s16x8*)&PQ[w][col][quad * 8];
        const s16x8 pf1 = *(const s16x8*)&PQ[w][col][32 + quad * 8];
        lacc = MFMA16(pf0, ones, lacc);
        lacc = MFMA16(pf1, ones, lacc);
#pragma unroll
        for (int nt = 0; nt < 4; ++nt) {
            s16x8 vf0 = *(const s16x8*)&Vts[p][nt * 16 + col][quad * 8];
            s16x8 vf1 = *(const s16x8*)&Vts[p][nt * 16 + col][32 + quad * 8];
            Oacc[nt] = MFMA16(pf0, vf0, Oacc[nt]);
            Oacc[nt] = MFMA16(pf1, vf1, Oacc[nt]);
        }

        if (kb < qb) {  // LDS-write prefetched tile into the other buffer
            *(uint4*)&Ks[p ^ 1][rs][cs]  = kreg;
            *(uint4*)&Vts[p ^ 1][rs][cs] = vreg;
        }
        __syncthreads();  // ONE barrier per iter
    }

    // epilogue: O / l  ->  obuf [b][l][h][64]  (bf16)
    const int h = hp * 2 + hl;
#pragma unroll
    for (int r = 0; r < 4; ++r) {
        float inv = 1.0f / lacc[r];
        size_t base = (((size_t)b * 2048 + qg + r) * 16 + h) * 64;
#pragma unroll
        for (int nt = 0; nt < 4; ++nt)
            obuf[base + nt * 16 + col] = f2bf(Oacc[nt][r] * inv);
    }
}

// ---------- launch ----------
extern "C" void kernel_launch(void* const* d_in, const int* in_sizes, int n_in,
                              void* d_out, int out_size, void* d_ws, size_t ws_size,
                              hipStream_t stream) {
    (void)in_sizes; (void)n_in; (void)out_size; (void)ws_size;
    const float* x     = (const float*)d_in[0];  // (2,2048,1024) fp32
    const float* Wqkv  = (const float*)d_in[1];  // (1152,1024)  fp32
    const float* gamma = (const float*)d_in[2];  // (1152,)      fp32
    const float* beta  = (const float*)d_in[3];  // (1152,)      fp32
    const float* Wfc   = (const float*)d_in[4];  // (1024,1024)  fp32
    float* out = (float*)d_out;                  // (2,2048,1024) fp32

    // ws >= 22,806,528 B (proven in round 5)
    char* ws = (char*)d_ws;
    unsigned short* xb   = (unsigned short*)ws;               // 8,388,608
    unsigned short* Wqb  = (unsigned short*)(ws + 8388608);   // 2,359,296
    unsigned short* Wfb  = (unsigned short*)(ws + 10747904);  // 2,097,152
    unsigned short* qkvn = (unsigned short*)(ws + 12845056);  // 9,437,184
    unsigned short* vT   = (unsigned short*)(ws + 22282240);  //   524,288
    unsigned short* abuf = (unsigned short*)ws;               // alias xb (dead after gemm1)

    cvt_all<<<dim3(3136), 256, 0, stream>>>(x, Wqkv, Wfc, xb, Wqb, Wfb);
    gemm_mn<false><<<dim3(32, 18), 256, 0, stream>>>(xb, Wqb, qkvn, 1024, 1152);
    ln_split<<<dim3(4096), 256, 0, stream>>>(qkvn, gamma, beta, vT);
    attn_kernel<<<dim3(16, 32), 512, 0, stream>>>(qkvn, vT, abuf);
    gemm_mn<true><<<dim3(32, 16), 256, 0, stream>>>(abuf, Wfb, out, 1024, 1024);
}